// Round 5
// baseline (172.257 us; speedup 1.0000x reference)
//
#include <hip/hip_runtime.h>

#define NN 100000
#define NE 3200000
#define FEAT 128
#define EMBED 128

typedef __attribute__((ext_vector_type(8))) __bf16 bf16x8;
typedef __attribute__((ext_vector_type(8))) unsigned short ushort8;
typedef __attribute__((ext_vector_type(4))) float f32x4;

static __device__ __forceinline__ unsigned short f2bf(float f) {
    unsigned u = __float_as_uint(f);
    return (unsigned short)((u + 0x7FFFu + ((u >> 16) & 1u)) >> 16);  // RNE
}

// ---------------------------------------------------------------------------
// w fp32 [128][128] -> bf16 bits (ushort) [128][128]
// ---------------------------------------------------------------------------
__global__ void convert_w(const float* __restrict__ w, unsigned short* __restrict__ wbf) {
    int i = blockIdx.x * 256 + threadIdx.x;
    if (i < EMBED * FEAT) wbf[i] = f2bf(w[i]);
}

// ---------------------------------------------------------------------------
// h_bf[n][e] = bf16( sum_f x[n][f] * w[e][f] ), via mfma_f32_16x16x32_bf16.
// (unchanged -- memory-bound, ~15 us)
// ---------------------------------------------------------------------------
__global__ __launch_bounds__(256)
void gemm_xwT(const float* __restrict__ x, const unsigned short* __restrict__ wbf,
              unsigned short* __restrict__ hbf) {
    int wave = blockIdx.x * 4 + (threadIdx.x >> 6);
    long row0 = (long)wave * 16;
    if (row0 >= NN) return;
    int lane = threadIdx.x & 63;
    int r = lane & 15, kg = lane >> 4;

    const float4* x4 = (const float4*)x;  // [row*32 + fc4]
    const bf16x8* wb = (const bf16x8*)wbf;

    bf16x8 afr[4];
#pragma unroll
    for (int ks = 0; ks < 4; ++ks) {
        long base = (row0 + r) * 32 + ks * 8 + kg * 2;
        float4 v0 = x4[base];
        float4 v1 = x4[base + 1];
        float xf[8] = {v0.x, v0.y, v0.z, v0.w, v1.x, v1.y, v1.z, v1.w};
        ushort8 au;
#pragma unroll
        for (int e = 0; e < 8; ++e) au[e] = f2bf(xf[e]);
        afr[ks] = __builtin_bit_cast(bf16x8, au);
    }

    f32x4 acc[8];
#pragma unroll
    for (int nt = 0; nt < 8; ++nt) acc[nt] = (f32x4){0.f, 0.f, 0.f, 0.f};

#pragma unroll
    for (int nt = 0; nt < 8; ++nt) {
#pragma unroll
        for (int ks = 0; ks < 4; ++ks) {
            bf16x8 b = wb[(nt * 16 + r) * 16 + ks * 4 + kg];
            acc[nt] = __builtin_amdgcn_mfma_f32_16x16x32_bf16(afr[ks], b, acc[nt], 0, 0, 0);
        }
    }

#pragma unroll
    for (int nt = 0; nt < 8; ++nt) {
#pragma unroll
        for (int reg = 0; reg < 4; ++reg) {
            hbf[(row0 + kg * 4 + reg) * 128 + nt * 16 + r] = f2bf(acc[nt][reg]);
        }
    }
}

// ---------------------------------------------------------------------------
// CSR row offsets from sorted edge_dst via per-node lower_bound.
// ---------------------------------------------------------------------------
__global__ void build_rowptr(const int* __restrict__ dst, int* __restrict__ rowptr) {
    int n = blockIdx.x * blockDim.x + threadIdx.x;
    if (n > NN) return;
    int lo = 0, hi = NE;
    while (lo < hi) {
        int mid = (lo + hi) >> 1;
        if (dst[mid] < n) lo = mid + 1; else hi = mid;
    }
    rowptr[n] = lo;
}

// ---------------------------------------------------------------------------
// One wave per destination node; 16-edge super-window = 4 independent
// global_load_dwordx4 (4 KB/wave) issued into NAMED registers before any
// consume (static indexing -- rule #20). Metadata via wave-uniform scalar
// loads with scalar-clamped predication (branch-free; OOB edges get w=0 and
// a safe clamped address). #pragma unroll 2 lets window k+1's scalar loads
// and gathers hoist above window k's consumes (counted-vmcnt pipeline).
// Final combine: 2 shfl_xor rounds once per wave; q==0 lanes store.
// ---------------------------------------------------------------------------
#define LOADQ(j, vj, wjv)                                                     \
    {                                                                         \
        int b = i + 4 * (j);                                                  \
        int e0 = b + 0 > last ? last : b + 0;                                 \
        int e1 = b + 1 > last ? last : b + 1;                                 \
        int e2 = b + 2 > last ? last : b + 2;                                 \
        int e3 = b + 3 > last ? last : b + 3;                                 \
        int s0 = src[e0], s1 = src[e1], s2 = src[e2], s3 = src[e3];           \
        float w0 = b + 0 < end ? ew[e0] : 0.f;                                \
        float w1 = b + 1 < end ? ew[e1] : 0.f;                                \
        float w2 = b + 2 < end ? ew[e2] : 0.f;                                \
        float w3 = b + 3 < end ? ew[e3] : 0.f;                                \
        int si = q == 0 ? s0 : (q == 1 ? s1 : (q == 2 ? s2 : s3));            \
        wjv    = q == 0 ? w0 : (q == 1 ? w1 : (q == 2 ? w2 : w3));            \
        vj = h4[(unsigned)si * 16u + (unsigned)c];                            \
    }

#define CONS(vj, wjv)                                                         \
    acc[0] += wjv * __uint_as_float(vj.x << 16);                              \
    acc[1] += wjv * __uint_as_float(vj.x & 0xFFFF0000u);                      \
    acc[2] += wjv * __uint_as_float(vj.y << 16);                              \
    acc[3] += wjv * __uint_as_float(vj.y & 0xFFFF0000u);                      \
    acc[4] += wjv * __uint_as_float(vj.z << 16);                              \
    acc[5] += wjv * __uint_as_float(vj.z & 0xFFFF0000u);                      \
    acc[6] += wjv * __uint_as_float(vj.w << 16);                              \
    acc[7] += wjv * __uint_as_float(vj.w & 0xFFFF0000u);

__global__ __launch_bounds__(256, 2)
void aggregate(const unsigned int* __restrict__ h32, const float* __restrict__ ew,
               const int* __restrict__ src, const int* __restrict__ rowptr,
               float* __restrict__ out) {
    int wid = (int)((blockIdx.x * 256u + threadIdx.x) >> 6);
    int lane = threadIdx.x & 63;
    if (wid >= NN) return;
    int start = __builtin_amdgcn_readfirstlane(rowptr[wid]);
    int end   = __builtin_amdgcn_readfirstlane(rowptr[wid + 1]);
    int last = end - 1;

    int q = lane >> 4;
    int c = lane & 15;

    float acc[8];
#pragma unroll
    for (int j = 0; j < 8; ++j) acc[j] = 0.f;

    const uint4* h4 = (const uint4*)h32;  // [row*16 + c]

#pragma unroll 2
    for (int i = start; i < end; i += 16) {
        uint4 va, vb, vc, vd;
        float wa, wb, wc, wd;
        LOADQ(0, va, wa)
        LOADQ(1, vb, wb)
        LOADQ(2, vc, wc)
        LOADQ(3, vd, wd)
        CONS(va, wa)
        CONS(vb, wb)
        CONS(vc, wc)
        CONS(vd, wd)
    }

    // combine edge slots: lanes {l, l^16, l^32, l^48} share the same cols
#pragma unroll
    for (int j = 0; j < 8; ++j) {
        acc[j] += __shfl_xor(acc[j], 16);
        acc[j] += __shfl_xor(acc[j], 32);
    }

    if (q == 0) {
        float4* op = (float4*)(out + (long)wid * 128 + c * 8);
        op[0] = make_float4(acc[0], acc[1], acc[2], acc[3]);
        op[1] = make_float4(acc[4], acc[5], acc[6], acc[7]);
    }
}

extern "C" void kernel_launch(void* const* d_in, const int* in_sizes, int n_in,
                              void* d_out, int out_size, void* d_ws, size_t ws_size,
                              hipStream_t stream) {
    const float* x    = (const float*)d_in[0];
    const float* w    = (const float*)d_in[1];
    const float* ew   = (const float*)d_in[2];
    const int*   esrc = (const int*)d_in[3];
    const int*   edst = (const int*)d_in[4];
    float* out = (float*)d_out;

    unsigned short* hbf = (unsigned short*)d_ws;                       // 25.6 MB
    int* rowptr = (int*)((char*)d_ws + (size_t)NN * 128 * 2);          // +400 KB
    unsigned short* wbf = (unsigned short*)((char*)d_ws + (size_t)NN * 128 * 2 + 400016);

    convert_w<<<64, 256, 0, stream>>>(w, wbf);
    gemm_xwT<<<(NN / 16 + 3) / 4, 256, 0, stream>>>(x, wbf, hbf);
    build_rowptr<<<(NN + 1 + 255) / 256, 256, 0, stream>>>(edst, rowptr);
    aggregate<<<(NN * 64) / 256, 256, 0, stream>>>((const unsigned int*)hbf, ew, esrc, rowptr, out);
}